// Round 6
// baseline (1652.126 us; speedup 1.0000x reference)
//
#include <hip/hip_runtime.h>
#include <hip/hip_bf16.h>
#include <stdint.h>

typedef __hip_bfloat16 bf16;
typedef __attribute__((ext_vector_type(8))) __bf16 bf16x8;
typedef __attribute__((ext_vector_type(4))) float f32x4;

#define GN_EPS 1e-5f

__device__ __forceinline__ float silu_f(float x) {
  return x / (1.f + __expf(-x));
}

// dtype-dual scalar load: flag==1 -> f32 data, flag==0 -> bf16 data
__device__ __forceinline__ float ldf(const void* p, size_t i, int f) {
  return f ? ((const float*)p)[i]
           : __bfloat162float(((const bf16*)p)[i]);
}

// async global->LDS, 16B per lane. LDS dest is wave-uniform base (+lane*16 HW).
__device__ __forceinline__ void llds16(const void* g, void* l) {
  __builtin_amdgcn_global_load_lds(
      (const __attribute__((address_space(1))) unsigned int*)g,
      (__attribute__((address_space(3))) unsigned int*)l, 16, 0, 0);
}

// direct global->VGPR 16B load, full 64b VGPR address form (vmcnt ledger)
__device__ __forceinline__ void gload16(bf16x8& d, const bf16* addr) {
  asm volatile("global_load_dwordx4 %0, %1, off"
               : "=&v"(d) : "v"(addr) : "memory");
}

// ---------------- dtype detect: scan gn1_w as bf16 halves -------------------
__global__ void detect_k(const void* __restrict__ gn1w, int* __restrict__ flag) {
  if (threadIdx.x == 0 && blockIdx.x == 0) {
    const unsigned short* u = (const unsigned short*)gn1w;
    float mx = 0.f;
    for (int i = 0; i < 128; ++i) {
      unsigned int b = ((unsigned int)u[i]) << 16;
      float v = __uint_as_float(b);
      v = fabsf(v);
      if (!isnan(v) && v > mx) mx = v;
    }
    flag[0] = (mx > 1e4f) ? 1 : 0;
  }
}

// -------- transpose (K, CI, CO) -> chunked (K, CI/32, CO, 32), out bf16 -----
// Wf[k][cb][co][ci&31]: per-slab fragment loads are contiguous per 16-col group
__global__ void transpose_k(const void* __restrict__ in, bf16* __restrict__ out,
                            int CI, int CO, const int* __restrict__ flagp) {
  const int f = *flagp;
  int k = blockIdx.y;
  int ntco = CO >> 5;
  int tci = blockIdx.x / ntco, tco = blockIdx.x % ntco;
  __shared__ float t[32][33];
  int tx = threadIdx.x & 31, ty = threadIdx.x >> 5;
  size_t base = (size_t)k * CI * CO;
  bf16* dst = out + base;
#pragma unroll
  for (int j = 0; j < 4; ++j)
    t[ty + 8 * j][tx] =
        ldf(in, base + (size_t)(tci * 32 + ty + 8 * j) * CO + tco * 32 + tx, f);
  __syncthreads();
#pragma unroll
  for (int j = 0; j < 4; ++j)
    dst[(size_t)tci * (CO * 32) + (size_t)(tco * 32 + ty + 8 * j) * 32 + tx] =
        __float2bfloat16(t[tx][ty + 8 * j]);
}

// ---------------- group-norm stats: sum/sumsq per group ----
__global__ void gn_stats_k(const void* __restrict__ x, float* __restrict__ raw,
                           int rows, int C, const int* __restrict__ flagp) {
  const int f = *flagp;
  int tid = threadIdx.x;
  int rpb = 256 / C;
  int c = tid & (C - 1);
  int stripe = tid / C;
  float s = 0.f, sq = 0.f;
  for (int r = blockIdx.x * rpb + stripe; r < rows; r += gridDim.x * rpb) {
    float v = ldf(x, (size_t)r * C + c, f);
    s += v; sq += v * v;
  }
  __shared__ float ls[256], lq[256];
  ls[tid] = s; lq[tid] = sq;
  __syncthreads();
  if (tid < 32) {
    int per = C >> 5;
    float as = 0.f, aq = 0.f;
    for (int st = 0; st < rpb; ++st)
      for (int e = 0; e < per; ++e) {
        int idx = st * C + tid * per + e;
        as += ls[idx]; aq += lq[idx];
      }
    atomicAdd(&raw[tid], as);
    atomicAdd(&raw[32 + tid], aq);
  }
}

__global__ void gn_fin_k(const float* __restrict__ raw, float* __restrict__ fin,
                         float count) {
  int g = threadIdx.x;
  if (g < 32) {
    float mu = raw[g] / count;
    float var = fmaxf(raw[32 + g] / count - mu * mu, 0.f);
    fin[g] = mu;
    fin[32 + g] = rsqrtf(var + GN_EPS);
  }
}

// ---------------- build per-cell voxel slots (<=8 parents per 2x cell) ------
__global__ void slots_k(const int* __restrict__ seg, int* __restrict__ cnt,
                        int* __restrict__ slots, int N) {
  int i = blockIdx.x * 256 + threadIdx.x;
  if (i >= N) return;
  int s = seg[i];
  int p = atomicAdd(&cnt[s], 1);
  if (p < 8) slots[s * 8 + p] = i;
}

// ---------------- downsample: x_d = mean(f), h_d = mean(silu(gn1(f))) -------
__global__ void down_k(const void* __restrict__ feats, const int* __restrict__ slots,
                       const int* __restrict__ cnt, const float* __restrict__ fin1,
                       const void* __restrict__ gw, const void* __restrict__ gb,
                       bf16* __restrict__ xd, bf16* __restrict__ hd, int M,
                       const int* __restrict__ flagp) {
  const int f = *flagp;
  int cell = blockIdx.x * 2 + (threadIdx.x >> 7);
  int c = threadIdx.x & 127;
  if (cell >= M) return;
  int n = min(cnt[cell], 8);
  int g = c >> 2;
  float mu = fin1[g], is = fin1[32 + g];
  float w = ldf(gw, c, f), b = ldf(gb, c, f);
  float xs = 0.f, hs = 0.f;
  for (int j = 0; j < n; ++j) {
    int v = slots[cell * 8 + j];
    float fv = ldf(feats, (size_t)v * 128 + c, f);
    xs += fv;
    hs += silu_f((fv - mu) * is * w + b);
  }
  float inv = 1.f / (float)max(n, 1);
  xd[(size_t)cell * 128 + c] = __float2bfloat16(xs * inv);
  hd[(size_t)cell * 128 + c] = __float2bfloat16(hs * inv);
}

// ---------------- h2 = silu(gn2(h1)) in-place, vectorized bf16x8 ------------
__global__ void act2_k(bf16* __restrict__ h, const float* __restrict__ fin2,
                       const void* __restrict__ gw, const void* __restrict__ gb,
                       size_t total8, const int* __restrict__ flagp) {
  const int f = *flagp;
  size_t i = (size_t)blockIdx.x * 256 + threadIdx.x;
  if (i >= total8) return;
  int c0 = (int)((i * 8) & 255);       // 8 consecutive channels, same group
  int g = c0 >> 3;
  float mu = fin2[g], is = fin2[32 + g];
  bf16x8 v = *reinterpret_cast<bf16x8*>(h + i * 8);
  bf16x8 o;
#pragma unroll
  for (int j = 0; j < 8; ++j) {
    float x = (float)v[j];
    float t = (x - mu) * is * ldf(gw, c0 + j, f) + ldf(gb, c0 + j, f);
    o[j] = (__bf16)silu_f(t);
  }
  *reinterpret_cast<bf16x8*>(h + i * 8) = o;
}

// ---------------- gather-GEMM conv, v6b --------------------------------------
// BM=96 x BN=256, 512 threads (8 waves 2x4, wave tile 48x64, acc[3][4]=48).
// Same proven v4 schedule: A via global_load_lds into ring-4 LDS (chunk-
// swizzled), B direct global->reg double-buffered (full-64b-addr asm form),
// exact per-wave-class vmcnt ledger, 1 raw barrier per slab. Halved per-thread
// state (~120 regs) targets 2 blocks/CU = two ASYNC barrier groups so one
// block's MFMA phase hides the other's stage/wait phase. Tile count ~1508 is
// ~98% round-quantized at both 256 and 512 slots -> graceful degradation.
// nA (A-panels staged per wave per slab): waves 0-5 -> 1, waves 6-7 -> 0.
template <int CIN, bool SKIP>
__global__ __launch_bounds__(512, 2) void conv_k(
    const bf16* __restrict__ A, const bf16* __restrict__ Wt,
    const void* __restrict__ bias, const void* __restrict__ bias2,
    const bf16* __restrict__ Xd, const int* __restrict__ nbr,
    void* __restrict__ out, int M, int nwg, const void* __restrict__ zp,
    const int* __restrict__ biasflagp, const int* __restrict__ outflagp) {
  constexpr int NCB = CIN / 32;                  // slabs per neighbor tap
  constexpr int LOG_NCB = (CIN == 256) ? 3 : 2;
  constexpr int NT = 27 * NCB + (SKIP ? 4 : 0);  // total slabs (even)
  // LDS: A-ring 4x6KB | nbrT 27x96 ints = 34944 B
  __shared__ alignas(16) char smem[24576 + 10368];
  char* Aring = smem;
  int* nbrT = (int*)(smem + 24576);

  const int bflag = *biasflagp, oflag = *outflagp;
  const int tid = threadIdx.x;
  const int wave = tid >> 6, lane = tid & 63;
  const bool wlo = (wave < 6);

  // --- XCD-aware bijective block swizzle (m204) ---
  int bid = blockIdx.x;
  int q = nwg >> 3, r8 = nwg & 7, xcd = bid & 7, ix = bid >> 3;
  int wg = (xcd < r8 ? xcd * (q + 1) : r8 * (q + 1) + (xcd - r8) * q) + ix;
  const int row0 = wg * 96;

  // ---- fill nbr table: nbrT[k*96 + r] = nbr[(row0+r)*27 + k] (or -1) -------
  for (int i = tid; i < 27 * 96; i += 512) {
    int k = i / 96, r = i - k * 96;
    int g = row0 + r;
    int v = -1;
    if (g < M) v = nbr[(size_t)g * 27 + k];
    nbrT[i] = v;
  }
  __syncthreads();

  // staging: panel = 16 rows x 64B = one llds (lane -> row l>>2, chunk l&3)
  // 6 panels per slab; wave w<6 stages panel w.
  const int srow = lane >> 2;
  const int schk = lane & 3;

  auto stageA = [&](int t) {
    if (!wlo) return;
    char* Asl = Aring + (size_t)(t & 3) * 6144;
    const bool isW = (!SKIP) || (t < 27 * NCB);
    const int kk = t >> LOG_NCB;
    const int cb = isW ? (t & (NCB - 1)) : (t - 27 * NCB);
    const int cink = isW ? CIN : 128;
    const bf16* Ab = isW ? A : Xd;
    const int koff = cb * 32;
    int r = wave * 16 + srow;
    int src;
    if (isW) src = nbrT[kk * 96 + r];
    else { int g = row0 + r; src = (g < M) ? g : -1; }
    int lc = schk ^ ((r >> 1) & 3);
    const bf16* ga = (src >= 0) ? Ab + (size_t)src * cink + koff + lc * 8
                                : (const bf16*)zp;
    llds16(ga, Asl + (size_t)wave * 1024);
  };

  // fragment geometry
  const int mrow = lane & 15, quad = lane >> 4;
  const int wr = wave >> 2, wc = wave & 3;       // 2 x 4 wave grid
  const int cswz = (quad ^ ((mrow >> 1) & 3)) * 16;

  // B fragment element offsets (loop-invariant)
  int beoff[4];
#pragma unroll
  for (int j = 0; j < 4; ++j)
    beoff[j] = (wc * 64 + j * 16 + mrow) * 32 + quad * 8;

  auto loadB = [&](bf16x8 (&dst)[4], int t) {
    const bool isW = (!SKIP) || (t < 27 * NCB);
    const int kk = t >> LOG_NCB;
    const int cb = isW ? (t & (NCB - 1)) : (t - 27 * NCB);
    const bf16* base = Wt +
        (isW ? (size_t)kk * (256 * CIN) : (size_t)27 * (256 * CIN)) +
        (size_t)cb * (256 * 32);
#pragma unroll
    for (int j = 0; j < 4; ++j) gload16(dst[j], base + beoff[j]);
  };

  f32x4 acc[3][4] = {};

  auto compute = [&](int t, const bf16x8 (&bv)[4]) {
    const char* As = Aring + (size_t)(t & 3) * 6144 +
                     (size_t)(wr * 48 + mrow) * 64 + cswz;
    bf16x8 af[3];
#pragma unroll
    for (int i = 0; i < 3; ++i)
      af[i] = *reinterpret_cast<const bf16x8*>(As + i * (16 * 64));
    __builtin_amdgcn_s_setprio(1);
#pragma unroll
    for (int i = 0; i < 3; ++i)
#pragma unroll
      for (int j = 0; j < 4; ++j)
        acc[i][j] = __builtin_amdgcn_mfma_f32_16x16x32_bf16(af[i], bv[j],
                                                            acc[i][j], 0, 0, 0);
    __builtin_amdgcn_s_setprio(0);
  };

#define VMW(a, b)                                                        \
  do {                                                                   \
    if (wlo) asm volatile("s_waitcnt vmcnt(" #a ")" ::: "memory");       \
    else     asm volatile("s_waitcnt vmcnt(" #b ")" ::: "memory");       \
    __builtin_amdgcn_sched_barrier(0);                                   \
  } while (0)
#define BAR() __builtin_amdgcn_s_barrier()

  bf16x8 bX[4], bY[4];

  // prologue. Invariant entering each iteration (waves 0-5):
  //   outstanding = {A(s):1, A(s+1):1, B(s):4} = 6;  waves 6-7: {B(s):4}.
  stageA(0); stageA(1);
  loadB(bX, 0);

#pragma unroll 1
  for (int u = 0; u < NT / 2 - 1; ++u) {
    const int s = 2 * u;
    loadB(bY, s + 1);
    stageA(s + 2);
    VMW(5, 4);           // force A(s),A(s+1),B(s); keep B(s+1),A(s+2)
    BAR();
    compute(s, bX);
    loadB(bX, s + 2);
    stageA(s + 3);
    VMW(6, 4);           // force B(s+1); keep A(s+2),B(s+2),A(s+3)
    BAR();
    compute(s + 1, bY);
  }
  // tail: s = NT-2 (A(NT-2),A(NT-1),B(NT-2) outstanding for waves 0-5)
  loadB(bY, NT - 1);
  VMW(4, 4);             // force A(NT-2),A(NT-1),B(NT-2); keep B(NT-1)
  BAR();
  compute(NT - 2, bX);
  VMW(0, 0);
  BAR();
  compute(NT - 1, bY);

#undef VMW
#undef BAR

  // ---- epilogue: bias (+bias2), store. C/D: col=lane&15, row=quad*4+r ------
#pragma unroll
  for (int j = 0; j < 4; ++j) {
    int col = wc * 64 + j * 16 + mrow;
    float bvl = ldf(bias, col, bflag);
    if (SKIP) bvl += ldf(bias2, col, bflag);
#pragma unroll
    for (int i = 0; i < 3; ++i) {
      int rb = row0 + wr * 48 + i * 16 + quad * 4;
#pragma unroll
      for (int r = 0; r < 4; ++r) {
        int row = rb + r;
        if (row < M) {
          size_t idx = (size_t)row * 256 + col;
          float val = acc[i][j][r] + bvl;
          if (oflag) ((float*)out)[idx] = val;
          else ((bf16*)out)[idx] = __float2bfloat16(val);
        }
      }
    }
  }
}

extern "C" void kernel_launch(void* const* d_in, const int* in_sizes, int n_in,
                              void* d_out, int out_size, void* d_ws, size_t ws_size,
                              hipStream_t stream) {
  const void* feats = d_in[0];
  const void* gn1w = d_in[1];
  const void* gn1b = d_in[2];
  const void* W1 = d_in[3];
  const void* b1 = d_in[4];
  const void* gn2w = d_in[5];
  const void* gn2b = d_in[6];
  const void* W2 = d_in[7];
  const void* b2 = d_in[8];
  const void* Wsk = d_in[9];
  const void* bsk = d_in[10];
  const int* pool = (const int*)d_in[11];
  const int* nbr = (const int*)d_in[12];
  const int N = in_sizes[0] / 128;
  const int M = out_size / 256;

  char* ws = (char*)d_ws;
  auto aup = [](size_t x) { return (x + 255) & ~(size_t)255; };
  float* raw1 = (float*)(ws + 0);      // 64 f32
  float* raw2 = (float*)(ws + 256);    // 64 f32
  int* flag = (int*)(ws + 512);        // dtype flag (1 = f32 inputs)
  int* zeroflag = (int*)(ws + 516);    // always 0 (force-bf16 flag)
  const void* zp = (const void*)(ws + 768);  // zero page (memset below)
  int* cnt = (int*)(ws + 1024);        // M i32
  size_t o = aup(1024 + (size_t)M * 4);
  float* fin1 = (float*)(ws + o); o += 256;
  float* fin2 = (float*)(ws + o); o += 256;
  int* slots = (int*)(ws + o); o = aup(o + (size_t)M * 32);
  bf16* xd = (bf16*)(ws + o); o += (size_t)M * 256;
  bf16* hd = (bf16*)(ws + o); o += (size_t)M * 256;
  bf16* h1 = (bf16*)(ws + o); o += (size_t)M * 512;
  bf16* wt1 = (bf16*)(ws + o); o += (size_t)27 * 256 * 128 * 2;
  bf16* wt2 = (bf16*)(ws + o); o += ((size_t)27 * 256 * 256 + 256 * 128) * 2;
  (void)ws_size; (void)n_in;

  // zero stats + flags + zero-page + counts (ws is poisoned before every call)
  hipMemsetAsync(ws, 0, 1024 + (size_t)M * 4, stream);

  // dtype detection (writes flag)
  detect_k<<<1, 64, 0, stream>>>(gn1w, flag);

  // weight transposes -> chunked Wf[k][cb][co][32]; Wskip appended to wt2
  transpose_k<<<dim3(4 * 8, 27), 256, 0, stream>>>(W1, wt1, 128, 256, flag);
  transpose_k<<<dim3(8 * 8, 27), 256, 0, stream>>>(W2, wt2, 256, 256, flag);
  transpose_k<<<dim3(4 * 8, 1), 256, 0, stream>>>(
      Wsk, wt2 + (size_t)27 * 256 * 256, 128, 256, flag);

  // GN1 stats over all N voxels
  gn_stats_k<<<512, 256, 0, stream>>>(feats, raw1, N, 128, flag);
  gn_fin_k<<<1, 64, 0, stream>>>(raw1, fin1, (float)N * 4.f);

  // downsample structure + gather
  slots_k<<<(N + 255) / 256, 256, 0, stream>>>(pool, cnt, slots, N);
  down_k<<<(M + 1) / 2, 256, 0, stream>>>(feats, slots, cnt, fin1, gn1w, gn1b,
                                          xd, hd, M, flag);

  const int nwg = (M + 95) / 96;

  // conv1: h1 = gatherGEMM(hd, W1) + b1   (h1 is bf16 -> outflag = zeroflag)
  conv_k<128, false><<<nwg, 512, 0, stream>>>(
      hd, wt1, b1, nullptr, nullptr, nbr, h1, M, nwg, zp, flag, zeroflag);

  // GN2 + SiLU (in place on h1; h1 is bf16 -> force-bf16 flag for stats)
  gn_stats_k<<<512, 256, 0, stream>>>(h1, raw2, M, 256, zeroflag);
  gn_fin_k<<<1, 64, 0, stream>>>(raw2, fin2, (float)M * 8.f);
  act2_k<<<(int)(((size_t)M * 32 + 255) / 256), 256, 0, stream>>>(
      h1, fin2, gn2w, gn2b, (size_t)M * 32, flag);

  // conv2 + fused skip (28th "neighbor" = self over xd with Wskip^T) + b2+bskip
  conv_k<256, true><<<nwg, 512, 0, stream>>>(
      h1, wt2, b2, bsk, xd, nbr, d_out, M, nwg, zp, flag, flag);
}

// Round 8
// 1555.065 us; speedup vs baseline: 1.0624x; 1.0624x over previous
//
#include <hip/hip_runtime.h>
#include <hip/hip_bf16.h>
#include <stdint.h>

typedef __hip_bfloat16 bf16;
typedef __attribute__((ext_vector_type(8))) __bf16 bf16x8;
typedef __attribute__((ext_vector_type(4))) float f32x4;

#define GN_EPS 1e-5f

__device__ __forceinline__ float silu_f(float x) {
  return x / (1.f + __expf(-x));
}

// dtype-dual scalar load: flag==1 -> f32 data, flag==0 -> bf16 data
__device__ __forceinline__ float ldf(const void* p, size_t i, int f) {
  return f ? ((const float*)p)[i]
           : __bfloat162float(((const bf16*)p)[i]);
}

// async global->LDS, 16B per lane. LDS dest is wave-uniform base (+lane*16 HW).
__device__ __forceinline__ void llds16(const void* g, void* l) {
  __builtin_amdgcn_global_load_lds(
      (const __attribute__((address_space(1))) unsigned int*)g,
      (__attribute__((address_space(3))) unsigned int*)l, 16, 0, 0);
}

// direct global->VGPR 16B load, full 64b VGPR address form (vmcnt ledger)
__device__ __forceinline__ void gload16(bf16x8& d, const bf16* addr) {
  asm volatile("global_load_dwordx4 %0, %1, off"
               : "=&v"(d) : "v"(addr) : "memory");
}

// ---------------- dtype detect: scan gn1_w as bf16 halves -------------------
__global__ void detect_k(const void* __restrict__ gn1w, int* __restrict__ flag) {
  if (threadIdx.x == 0 && blockIdx.x == 0) {
    const unsigned short* u = (const unsigned short*)gn1w;
    float mx = 0.f;
    for (int i = 0; i < 128; ++i) {
      unsigned int b = ((unsigned int)u[i]) << 16;
      float v = __uint_as_float(b);
      v = fabsf(v);
      if (!isnan(v) && v > mx) mx = v;
    }
    flag[0] = (mx > 1e4f) ? 1 : 0;
  }
}

// -------- transpose (K, CI, CO) -> chunked (K, CI/32, CO, 32), out bf16 -----
// Wf[k][cb][co][ci&31]: per-slab fragment loads are contiguous per 16-col group
__global__ void transpose_k(const void* __restrict__ in, bf16* __restrict__ out,
                            int CI, int CO, const int* __restrict__ flagp) {
  const int f = *flagp;
  int k = blockIdx.y;
  int ntco = CO >> 5;
  int tci = blockIdx.x / ntco, tco = blockIdx.x % ntco;
  __shared__ float t[32][33];
  int tx = threadIdx.x & 31, ty = threadIdx.x >> 5;
  size_t base = (size_t)k * CI * CO;
  bf16* dst = out + base;
#pragma unroll
  for (int j = 0; j < 4; ++j)
    t[ty + 8 * j][tx] =
        ldf(in, base + (size_t)(tci * 32 + ty + 8 * j) * CO + tco * 32 + tx, f);
  __syncthreads();
#pragma unroll
  for (int j = 0; j < 4; ++j)
    dst[(size_t)tci * (CO * 32) + (size_t)(tco * 32 + ty + 8 * j) * 32 + tx] =
        __float2bfloat16(t[tx][ty + 8 * j]);
}

// ---------------- group-norm stats: sum/sumsq per group ----
__global__ void gn_stats_k(const void* __restrict__ x, float* __restrict__ raw,
                           int rows, int C, const int* __restrict__ flagp) {
  const int f = *flagp;
  int tid = threadIdx.x;
  int rpb = 256 / C;
  int c = tid & (C - 1);
  int stripe = tid / C;
  float s = 0.f, sq = 0.f;
  for (int r = blockIdx.x * rpb + stripe; r < rows; r += gridDim.x * rpb) {
    float v = ldf(x, (size_t)r * C + c, f);
    s += v; sq += v * v;
  }
  __shared__ float ls[256], lq[256];
  ls[tid] = s; lq[tid] = sq;
  __syncthreads();
  if (tid < 32) {
    int per = C >> 5;
    float as = 0.f, aq = 0.f;
    for (int st = 0; st < rpb; ++st)
      for (int e = 0; e < per; ++e) {
        int idx = st * C + tid * per + e;
        as += ls[idx]; aq += lq[idx];
      }
    atomicAdd(&raw[tid], as);
    atomicAdd(&raw[32 + tid], aq);
  }
}

__global__ void gn_fin_k(const float* __restrict__ raw, float* __restrict__ fin,
                         float count) {
  int g = threadIdx.x;
  if (g < 32) {
    float mu = raw[g] / count;
    float var = fmaxf(raw[32 + g] / count - mu * mu, 0.f);
    fin[g] = mu;
    fin[32 + g] = rsqrtf(var + GN_EPS);
  }
}

// ---------------- build per-cell voxel slots (<=8 parents per 2x cell) ------
__global__ void slots_k(const int* __restrict__ seg, int* __restrict__ cnt,
                        int* __restrict__ slots, int N) {
  int i = blockIdx.x * 256 + threadIdx.x;
  if (i >= N) return;
  int s = seg[i];
  int p = atomicAdd(&cnt[s], 1);
  if (p < 8) slots[s * 8 + p] = i;
}

// ---------------- downsample: x_d = mean(f), h_d = mean(silu(gn1(f))) -------
__global__ void down_k(const void* __restrict__ feats, const int* __restrict__ slots,
                       const int* __restrict__ cnt, const float* __restrict__ fin1,
                       const void* __restrict__ gw, const void* __restrict__ gb,
                       bf16* __restrict__ xd, bf16* __restrict__ hd, int M,
                       const int* __restrict__ flagp) {
  const int f = *flagp;
  int cell = blockIdx.x * 2 + (threadIdx.x >> 7);
  int c = threadIdx.x & 127;
  if (cell >= M) return;
  int n = min(cnt[cell], 8);
  int g = c >> 2;
  float mu = fin1[g], is = fin1[32 + g];
  float w = ldf(gw, c, f), b = ldf(gb, c, f);
  float xs = 0.f, hs = 0.f;
  for (int j = 0; j < n; ++j) {
    int v = slots[cell * 8 + j];
    float fv = ldf(feats, (size_t)v * 128 + c, f);
    xs += fv;
    hs += silu_f((fv - mu) * is * w + b);
  }
  float inv = 1.f / (float)max(n, 1);
  xd[(size_t)cell * 128 + c] = __float2bfloat16(xs * inv);
  hd[(size_t)cell * 128 + c] = __float2bfloat16(hs * inv);
}

// ---------------- h2 = silu(gn2(h1)) in-place, vectorized bf16x8 ------------
__global__ void act2_k(bf16* __restrict__ h, const float* __restrict__ fin2,
                       const void* __restrict__ gw, const void* __restrict__ gb,
                       size_t total8, const int* __restrict__ flagp) {
  const int f = *flagp;
  size_t i = (size_t)blockIdx.x * 256 + threadIdx.x;
  if (i >= total8) return;
  int c0 = (int)((i * 8) & 255);       // 8 consecutive channels, same group
  int g = c0 >> 3;
  float mu = fin2[g], is = fin2[32 + g];
  bf16x8 v = *reinterpret_cast<bf16x8*>(h + i * 8);
  bf16x8 o;
#pragma unroll
  for (int j = 0; j < 8; ++j) {
    float x = (float)v[j];
    float t = (x - mu) * is * ldf(gw, c0 + j, f) + ldf(gb, c0 + j, f);
    o[j] = (__bf16)silu_f(t);
  }
  *reinterpret_cast<bf16x8*>(h + i * 8) = o;
}

// ---------------- gather-GEMM conv, v7 ---------------------------------------
// v4 structure (proven 556us) with BK=64 slabs: BM=192 x BN=256, 512 threads
// (8 waves 2x4, wave tile 96x64, acc[6][4]). A: ring-2 x 24KB LDS via
// global_load_lds, rows 128B, chunk swizzle c^(row&7) (64 lanes -> 64 distinct
// 16B slots per frag read). B: direct global->reg, double-buffered (8 frags).
// Uniform ledger: every wave issues 8 B-loads + 3 A-panels per slab ->
// single vmcnt(11) keeps exactly one slab in flight across barriers (T4).
// Halves phase count vs BK=32 -> barrier/wait amortization doubles.
// nbrT fill is coalesced (linear read of nbr, transposed store).
template <int CIN, bool SKIP>
__global__ __launch_bounds__(512, 2) void conv_k(
    const bf16* __restrict__ A, const bf16* __restrict__ Wt,
    const void* __restrict__ bias, const void* __restrict__ bias2,
    const bf16* __restrict__ Xd, const int* __restrict__ nbr,
    void* __restrict__ out, int M, int nwg, const void* __restrict__ zp,
    const int* __restrict__ biasflagp, const int* __restrict__ outflagp) {
  constexpr int NCB = CIN / 64;                  // 64-k slabs per neighbor tap
  constexpr int LOG_NCB = (CIN == 256) ? 2 : 1;
  constexpr int NT = 27 * NCB + (SKIP ? 2 : 0);  // total slabs (even)
  // LDS: A-ring 2x24KB | nbrT 27x192 ints = 69888 B
  __shared__ alignas(16) char smem[49152 + 20736];
  char* Aring = smem;
  int* nbrT = (int*)(smem + 49152);

  const int bflag = *biasflagp, oflag = *outflagp;
  const int tid = threadIdx.x;
  const int wave = tid >> 6, lane = tid & 63;

  // --- XCD-aware bijective block swizzle (m204) ---
  int bid = blockIdx.x;
  int q = nwg >> 3, r8 = nwg & 7, xcd = bid & 7, ix = bid >> 3;
  int wg = (xcd < r8 ? xcd * (q + 1) : r8 * (q + 1) + (xcd - r8) * q) + ix;
  const int row0 = wg * 192;

  // ---- nbrT fill, coalesced: read nbr row-major, store k-major -------------
  // nbrT[k*192 + r] = nbr[(row0+r)*27 + k] (or -1 when row OOB)
  for (int i = tid; i < 27 * 192; i += 512) {
    int r = i / 27, k = i - r * 27;
    int g = row0 + r;
    int v = (g < M) ? nbr[(size_t)row0 * 27 + i] : -1;
    nbrT[k * 192 + r] = v;
  }
  __syncthreads();

  // staging: panel = 8 rows x 128B = one llds; lane -> row=l>>3, chunk=l&7.
  // 24 panels per slab; wave w stages panels {3w, 3w+1, 3w+2}. nA = 3 uniform.
  const int prow = lane >> 3;          // row within panel (== row&7)
  const int schk = lane & 7;
  const int gc = schk ^ prow;          // pre-swizzled source chunk (m173)

  auto stageA = [&](int t) {
    char* Asl = Aring + (size_t)(t & 1) * 24576;
    const bool isW = (!SKIP) || (t < 27 * NCB);
    const int kk = t >> LOG_NCB;
    const int cb = isW ? (t & (NCB - 1)) : (t - 27 * NCB);
    const int cink = isW ? CIN : 128;
    const bf16* Ab = isW ? A : Xd;
    const int koff = cb * 64;
#pragma unroll
    for (int p = 0; p < 3; ++p) {
      int panel = wave * 3 + p;
      int r = panel * 8 + prow;
      int src;
      if (isW) src = nbrT[kk * 192 + r];
      else { int g = row0 + r; src = (g < M) ? g : -1; }
      const bf16* ga = (src >= 0) ? Ab + (size_t)src * cink + koff + gc * 8
                                  : (const bf16*)zp;
      llds16(ga, Asl + (size_t)panel * 1024);
    }
  };

  // fragment geometry
  const int mrow = lane & 15, quad = lane >> 4;
  const int wr = wave >> 2, wc = wave & 3;       // 2 x 4 wave grid
  const int sw0 = ((quad) ^ (mrow & 7)) * 16;        // ks=0 chunk byte
  const int sw1 = ((4 + quad) ^ (mrow & 7)) * 16;    // ks=1 chunk byte

  // B fragment element offsets (loop-invariant); frag (ks,j) at
  // base + ks*8192 + beoff[j]
  int beoff[4];
#pragma unroll
  for (int j = 0; j < 4; ++j)
    beoff[j] = (wc * 64 + j * 16 + mrow) * 32 + quad * 8;

  auto loadB = [&](bf16x8 (&dst)[8], int t) {
    const bool isW = (!SKIP) || (t < 27 * NCB);
    const int kk = t >> LOG_NCB;
    const int cb = isW ? (t & (NCB - 1)) : (t - 27 * NCB);
    const bf16* base = Wt +
        (isW ? (size_t)kk * (256 * CIN) : (size_t)27 * (256 * CIN)) +
        (size_t)cb * (256 * 64);
#pragma unroll
    for (int ks = 0; ks < 2; ++ks)
#pragma unroll
      for (int j = 0; j < 4; ++j)
        gload16(dst[ks * 4 + j], base + ks * 8192 + beoff[j]);
  };

  f32x4 acc[6][4] = {};

  auto compute = [&](int t, const bf16x8 (&bv)[8]) {
    const char* As = Aring + (size_t)(t & 1) * 24576 +
                     (size_t)(wr * 96 + mrow) * 128;
    __builtin_amdgcn_s_setprio(1);
#pragma unroll
    for (int i = 0; i < 6; ++i) {
      bf16x8 a0 = *reinterpret_cast<const bf16x8*>(As + i * (16 * 128) + sw0);
      bf16x8 a1 = *reinterpret_cast<const bf16x8*>(As + i * (16 * 128) + sw1);
#pragma unroll
      for (int j = 0; j < 4; ++j) {
        acc[i][j] = __builtin_amdgcn_mfma_f32_16x16x32_bf16(a0, bv[j],
                                                            acc[i][j], 0, 0, 0);
        acc[i][j] = __builtin_amdgcn_mfma_f32_16x16x32_bf16(a1, bv[4 + j],
                                                            acc[i][j], 0, 0, 0);
      }
    }
    __builtin_amdgcn_s_setprio(0);
  };

#define VMW(n)                                                           \
  do {                                                                   \
    asm volatile("s_waitcnt vmcnt(" #n ")" ::: "memory");                \
    __builtin_amdgcn_sched_barrier(0);                                   \
  } while (0)
#define BAR() __builtin_amdgcn_s_barrier()

  bf16x8 bX[8], bY[8];

  // prologue. Invariant entering each iteration: outstanding = {A(s):3, B(s):8}
  stageA(0);
  loadB(bX, 0);

#pragma unroll 1
  for (int u = 0; u < NT / 2 - 1; ++u) {
    const int s = 2 * u;
    loadB(bY, s + 1);
    stageA(s + 1);       // writes buf[(s+1)&1], last read by compute(s-1) [BAR]
    VMW(11);             // force A(s),B(s); keep A(s+1),B(s+1) in flight
    BAR();
    compute(s, bX);
    BAR();               // all waves done with buf[s&1]
    loadB(bX, s + 2);
    stageA(s + 2);       // overwrites buf[s&1]
    VMW(11);             // force A(s+1),B(s+1); keep A(s+2),B(s+2)
    BAR();
    compute(s + 1, bY);
    BAR();
  }
  // tail: s = NT-2; entering: {A(NT-2):3, B(NT-2):8}
  loadB(bY, NT - 1);
  stageA(NT - 1);
  VMW(11);
  BAR();
  compute(NT - 2, bX);
  BAR();
  VMW(0);
  BAR();
  compute(NT - 1, bY);

#undef VMW
#undef BAR

  // ---- epilogue: bias (+bias2), store. C/D: col=lane&15, row=quad*4+r ------
#pragma unroll
  for (int j = 0; j < 4; ++j) {
    int col = wc * 64 + j * 16 + mrow;
    float bvl = ldf(bias, col, bflag);
    if (SKIP) bvl += ldf(bias2, col, bflag);
#pragma unroll
    for (int i = 0; i < 6; ++i) {
      int rb = row0 + wr * 96 + i * 16 + quad * 4;
#pragma unroll
      for (int r = 0; r < 4; ++r) {
        int row = rb + r;
        if (row < M) {
          size_t idx = (size_t)row * 256 + col;
          float val = acc[i][j][r] + bvl;
          if (oflag) ((float*)out)[idx] = val;
          else ((bf16*)out)[idx] = __float2bfloat16(val);
        }
      }
    }
  }
}

extern "C" void kernel_launch(void* const* d_in, const int* in_sizes, int n_in,
                              void* d_out, int out_size, void* d_ws, size_t ws_size,
                              hipStream_t stream) {
  const void* feats = d_in[0];
  const void* gn1w = d_in[1];
  const void* gn1b = d_in[2];
  const void* W1 = d_in[3];
  const void* b1 = d_in[4];
  const void* gn2w = d_in[5];
  const void* gn2b = d_in[6];
  const void* W2 = d_in[7];
  const void* b2 = d_in[8];
  const void* Wsk = d_in[9];
  const void* bsk = d_in[10];
  const int* pool = (const int*)d_in[11];
  const int* nbr = (const int*)d_in[12];
  const int N = in_sizes[0] / 128;
  const int M = out_size / 256;

  char* ws = (char*)d_ws;
  auto aup = [](size_t x) { return (x + 255) & ~(size_t)255; };
  float* raw1 = (float*)(ws + 0);      // 64 f32
  float* raw2 = (float*)(ws + 256);    // 64 f32
  int* flag = (int*)(ws + 512);        // dtype flag (1 = f32 inputs)
  int* zeroflag = (int*)(ws + 516);    // always 0 (force-bf16 flag)
  const void* zp = (const void*)(ws + 768);  // zero page (memset below)
  int* cnt = (int*)(ws + 1024);        // M i32
  size_t o = aup(1024 + (size_t)M * 4);
  float* fin1 = (float*)(ws + o); o += 256;
  float* fin2 = (float*)(ws + o); o += 256;
  int* slots = (int*)(ws + o); o = aup(o + (size_t)M * 32);
  bf16* xd = (bf16*)(ws + o); o += (size_t)M * 256;
  bf16* hd = (bf16*)(ws + o); o += (size_t)M * 256;
  bf16* h1 = (bf16*)(ws + o); o += (size_t)M * 512;
  bf16* wt1 = (bf16*)(ws + o); o += (size_t)27 * 256 * 128 * 2;
  bf16* wt2 = (bf16*)(ws + o); o += ((size_t)27 * 256 * 256 + 256 * 128) * 2;
  (void)ws_size; (void)n_in;

  // zero stats + flags + zero-page + counts (ws is poisoned before every call)
  hipMemsetAsync(ws, 0, 1024 + (size_t)M * 4, stream);

  // dtype detection (writes flag)
  detect_k<<<1, 64, 0, stream>>>(gn1w, flag);

  // weight transposes -> chunked Wf[k][cb][co][32]; Wskip appended to wt2
  transpose_k<<<dim3(4 * 8, 27), 256, 0, stream>>>(W1, wt1, 128, 256, flag);
  transpose_k<<<dim3(8 * 8, 27), 256, 0, stream>>>(W2, wt2, 256, 256, flag);
  transpose_k<<<dim3(4 * 8, 1), 256, 0, stream>>>(
      Wsk, wt2 + (size_t)27 * 256 * 256, 128, 256, flag);

  // GN1 stats over all N voxels
  gn_stats_k<<<512, 256, 0, stream>>>(feats, raw1, N, 128, flag);
  gn_fin_k<<<1, 64, 0, stream>>>(raw1, fin1, (float)N * 4.f);

  // downsample structure + gather
  slots_k<<<(N + 255) / 256, 256, 0, stream>>>(pool, cnt, slots, N);
  down_k<<<(M + 1) / 2, 256, 0, stream>>>(feats, slots, cnt, fin1, gn1w, gn1b,
                                          xd, hd, M, flag);

  const int nwg = (M + 191) / 192;

  // conv1: h1 = gatherGEMM(hd, W1) + b1   (h1 is bf16 -> outflag = zeroflag)
  conv_k<128, false><<<nwg, 512, 0, stream>>>(
      hd, wt1, b1, nullptr, nullptr, nbr, h1, M, nwg, zp, flag, zeroflag);

  // GN2 + SiLU (in place on h1; h1 is bf16 -> force-bf16 flag for stats)
  gn_stats_k<<<512, 256, 0, stream>>>(h1, raw2, M, 256, zeroflag);
  gn_fin_k<<<1, 64, 0, stream>>>(raw2, fin2, (float)M * 8.f);
  act2_k<<<(int)(((size_t)M * 32 + 255) / 256), 256, 0, stream>>>(
      h1, fin2, gn2w, gn2b, (size_t)M * 32, flag);

  // conv2 + fused skip (28th "neighbor" = self over xd with Wskip^T) + b2+bskip
  conv_k<256, true><<<nwg, 512, 0, stream>>>(
      h1, wt2, b2, bsk, xd, nbr, d_out, M, nwg, zp, flag, flag);
}